// Round 6
// baseline (296.618 us; speedup 1.0000x reference)
//
#include <hip/hip_runtime.h>
#include <hip/hip_bf16.h>

#define N_NODES_C 100000
#define N_GRAPHS_C 64
#define FDIM 128
#define NXCD 8
#define NODES_PER_XCD 12500   // N_NODES_C / NXCD
#define PART_BLOCKS 64        // blocks per XCD group

typedef _Float16 half8v __attribute__((ext_vector_type(8)));
typedef __attribute__((ext_vector_type(4))) float f32x4;

__device__ __forceinline__ unsigned short f2h(float f) {
    union { _Float16 h; unsigned short u; } v; v.h = (_Float16)f; return v.u;
}
__device__ __forceinline__ float h2flo(unsigned u) {
    union { unsigned short s; _Float16 h; } v; v.s = (unsigned short)u; return (float)v.h;
}
__device__ __forceinline__ float h2fhi(unsigned u) {
    union { unsigned short s; _Float16 h; } v; v.s = (unsigned short)(u >> 16); return (float)v.h;
}

// ---------------------------------------------------------------- XCD-partitioned degree histogram
// blockIdx&7 selects an XCD-owned target range; group grid-strides the full edge list.
// All atomics on cnt[] land in one XCD's L2 -> no cross-XCD line ping-pong.
__global__ __launch_bounds__(256) void hist_part(const int* __restrict__ tgt,
                                                 int* __restrict__ cnt, int E) {
    const int grp = blockIdx.x & (NXCD - 1);
    const int bin = blockIdx.x >> 3;
    const int lo = grp * NODES_PER_XCD;
    const int hi = lo + NODES_PER_XCD;
    const int stride = PART_BLOCKS * 256;
    for (int e = bin * 256 + threadIdx.x; e < E; e += stride) {
        int t = tgt[e];
        if (t >= lo && t < hi) atomicAdd(&cnt[t], 1);
    }
}

// ---------------------------------------------------------------- exclusive scan (1024/block)
__global__ __launch_bounds__(256) void scan_block(const int* __restrict__ deg,
                                                  int* __restrict__ out,
                                                  int* __restrict__ bsum, int n) {
    __shared__ int ts[256];
    const int t = threadIdx.x;
    const int base = blockIdx.x * 1024 + t * 4;
    int4 v = make_int4(0, 0, 0, 0);
    if (base + 3 < n) v = *(const int4*)(deg + base);
    else {
        if (base + 0 < n) v.x = deg[base + 0];
        if (base + 1 < n) v.y = deg[base + 1];
        if (base + 2 < n) v.z = deg[base + 2];
        if (base + 3 < n) v.w = deg[base + 3];
    }
    int s0 = v.x, s1 = s0 + v.y, s2 = s1 + v.z, s3 = s2 + v.w;
    ts[t] = s3;
    __syncthreads();
    for (int off = 1; off < 256; off <<= 1) {
        int val = (t >= off) ? ts[t - off] : 0;
        __syncthreads();
        ts[t] += val;
        __syncthreads();
    }
    int excl = (t > 0) ? ts[t - 1] : 0;
    int4 o = make_int4(excl, excl + s0, excl + s1, excl + s2);
    if (base + 3 < n) *(int4*)(out + base) = o;
    else {
        if (base + 0 < n) out[base + 0] = o.x;
        if (base + 1 < n) out[base + 1] = o.y;
        if (base + 2 < n) out[base + 2] = o.z;
        if (base + 3 < n) out[base + 3] = o.w;
    }
    if (t == 255) bsum[blockIdx.x] = ts[255];
}

__global__ __launch_bounds__(256) void scan_sums(int* __restrict__ bsum, int nb) {
    __shared__ int s[256];
    const int t = threadIdx.x;
    s[t] = (t < nb) ? bsum[t] : 0;
    __syncthreads();
    for (int off = 1; off < 256; off <<= 1) {
        int val = (t >= off) ? s[t - off] : 0;
        __syncthreads();
        s[t] += val;
        __syncthreads();
    }
    if (t < nb) bsum[t] = (t > 0) ? s[t - 1] : 0;
}

// scan finalize + inv_deg fused
__global__ __launch_bounds__(256) void scan_add(int* __restrict__ out,
                                                const int* __restrict__ bsum,
                                                const int* __restrict__ degi,
                                                float* __restrict__ invd,
                                                int n, int total) {
    int i = blockIdx.x * 256 + threadIdx.x;
    if (i < n) {
        out[i] += bsum[i >> 10];
        invd[i] = 1.0f / (float)max(degi[i], 1);
    }
    if (i == 0) out[n] = total;
}

// ---------------------------------------------------------------- XCD-partitioned CSR scatter
// Same partitioning: cursor atomics XCD-local; csr[p] writes land in a contiguous
// 320 KB slice owned by one XCD -> stays L2-resident, single final writeback.
__global__ __launch_bounds__(256) void scatter_part(const int* __restrict__ src,
                                                    const int* __restrict__ tgt,
                                                    const int* __restrict__ rowstart,
                                                    int* __restrict__ cursor,
                                                    int* __restrict__ csr, int E) {
    const int grp = blockIdx.x & (NXCD - 1);
    const int bin = blockIdx.x >> 3;
    const int lo = grp * NODES_PER_XCD;
    const int hi = lo + NODES_PER_XCD;
    const int stride = PART_BLOCKS * 256;
    for (int e = bin * 256 + threadIdx.x; e < E; e += stride) {
        int t = tgt[e];
        if (t >= lo && t < hi) {
            int p = rowstart[t] + atomicAdd(&cursor[t], 1);
            csr[p] = src[e];
        }
    }
}

// ---------------------------------------------------------------- graph boundaries (batch sorted)
__global__ __launch_bounds__(64) void graph_cnt_kernel(const int* __restrict__ batch,
                                                       int* __restrict__ gstart,
                                                       float* __restrict__ gcnt, int n) {
    int g = threadIdx.x;  // 0..63
    int lo = 0, hi = n;
    while (lo < hi) { int m = (lo + hi) >> 1; if (batch[m] < g) lo = m + 1; else hi = m; }
    int lb = lo;
    lo = 0; hi = n;
    while (lo < hi) { int m = (lo + hi) >> 1; if (batch[m] < g + 1) lo = m + 1; else hi = m; }
    gstart[g] = lb;
    gcnt[g] = (float)(lo - lb);
    if (g == 0) gstart[64] = n;
}

// ---------------------------------------------------------------- fp32 -> fp16 convert (8/thread)
__global__ __launch_bounds__(256) void conv_f16(const float* __restrict__ in,
                                                unsigned short* __restrict__ out, int n8) {
    int i = blockIdx.x * 256 + threadIdx.x;
    if (i < n8) {
        float4 v0 = *(const float4*)(in + (size_t)i * 8);
        float4 v1 = *(const float4*)(in + (size_t)i * 8 + 4);
        half8v o;
        o[0] = (_Float16)v0.x; o[1] = (_Float16)v0.y; o[2] = (_Float16)v0.z; o[3] = (_Float16)v0.w;
        o[4] = (_Float16)v1.x; o[5] = (_Float16)v1.y; o[6] = (_Float16)v1.z; o[7] = (_Float16)v1.w;
        *(half8v*)(out + (size_t)i * 8) = o;
    }
}

// ---------------------------------------------------------------- weight prep: fragment-ordered fp16
// chunk c (0..63): khalf=c>>5, nf=(c>>2)&7, ks4=c&3 ; elem i (0..511): l=i>>3, e=i&7
// j = nf*16 + (l&15) ; k = khalf*128 + ks4*32 + (l>>4)*8 + e
__global__ __launch_bounds__(256) void prep_w(const float* __restrict__ Wl,
                                              const float* __restrict__ Wr,
                                              unsigned short* __restrict__ outW) {
    int id = blockIdx.x * 256 + threadIdx.x;  // 0..32767
    int c = id >> 9, i = id & 511;
    int l = i >> 3, e = i & 7;
    int khalf = c >> 5, nf = (c >> 2) & 7, ks4 = c & 3;
    int j = nf * 16 + (l & 15);
    int k = khalf * 128 + ks4 * 32 + ((l >> 4) << 3) + e;
    float w = (k < 128) ? Wl[k * 128 + j] : Wr[(k - 128) * 128 + j];
    outW[id] = f2h(w);
}

// ---------------------------------------------------------------- CSR mean-aggregate (fp16 in/out)
// 16 lanes per node (4 nodes/wave); 16B row loads; unroll-4 edge pipeline.
__device__ __forceinline__ void acc8h(float* a, half8v v) {
#pragma unroll
    for (int j = 0; j < 8; ++j) a[j] += (float)v[j];
}

__global__ __launch_bounds__(256) void agg_f16(const unsigned short* __restrict__ Xin,
                                               const int* __restrict__ csr,
                                               const int* __restrict__ rowstart,
                                               const float* __restrict__ invd,
                                               unsigned short* __restrict__ Agg, int N) {
    const int grp  = threadIdx.x >> 4;            // 0..15
    const int node = blockIdx.x * 16 + grp;
    if (node >= N) return;
    const int lane = threadIdx.x & 15;
    const int beg = rowstart[node];
    const int end = rowstart[node + 1];

    float a[8] = {0.f, 0.f, 0.f, 0.f, 0.f, 0.f, 0.f, 0.f};
    int e = beg;
    for (; e + 3 < end; e += 4) {
        int s0 = csr[e + 0];
        int s1 = csr[e + 1];
        int s2 = csr[e + 2];
        int s3 = csr[e + 3];
        half8v v0 = *(const half8v*)(Xin + ((size_t)s0 << 7) + lane * 8);
        half8v v1 = *(const half8v*)(Xin + ((size_t)s1 << 7) + lane * 8);
        half8v v2 = *(const half8v*)(Xin + ((size_t)s2 << 7) + lane * 8);
        half8v v3 = *(const half8v*)(Xin + ((size_t)s3 << 7) + lane * 8);
        acc8h(a, v0); acc8h(a, v1); acc8h(a, v2); acc8h(a, v3);
    }
    for (; e < end; ++e) {
        int s0 = csr[e];
        half8v v0 = *(const half8v*)(Xin + ((size_t)s0 << 7) + lane * 8);
        acc8h(a, v0);
    }

    float sc = invd[node];
    half8v o;
#pragma unroll
    for (int j = 0; j < 8; ++j) o[j] = (_Float16)(a[j] * sc);
    *(half8v*)(Agg + ((size_t)node << 7) + lane * 8) = o;
}

// ---------------------------------------------------------------- MFMA dual GEMM (fp16)
// H[r,:] = relu( [Agg(r)|X(r)] @ W + b ),  virtual K=256, fp16 in, fp16 out
// 256 thr = 4 waves; wave owns 32 rows x 128 cols (2 m-frags x 8 n-frags, 16x16x32 f16 MFMA)
// W staged per-khalf in 32 KiB LDS. SWAPPED operand order => D^T: lane holds one
// node-row, 4 consecutive j-cols in regs -> 8B packed stores.
__global__ __launch_bounds__(256) void gemm_mfma(const unsigned short* __restrict__ Agg,
                                                 const unsigned short* __restrict__ Xop,
                                                 const unsigned short* __restrict__ WtF,
                                                 const float* __restrict__ bias,
                                                 unsigned short* __restrict__ Hout, int N) {
    __shared__ unsigned short wlds[32 * 512];   // 32 KiB: one khalf, fragment-ordered

    const int t = threadIdx.x;
    const int wave = t >> 6;
    const int l = t & 63;
    const int rw = blockIdx.x * 128 + wave * 32;
    const int lrow = l & 15;
    const int lk = (l >> 4) << 3;

    f32x4 acc[2][8];
#pragma unroll
    for (int m = 0; m < 2; ++m)
#pragma unroll
        for (int nf = 0; nf < 8; ++nf) acc[m][nf] = (f32x4)(0.f);

    for (int khalf = 0; khalf < 2; ++khalf) {
        if (khalf) __syncthreads();   // previous compute done before overwrite
#pragma unroll
        for (int rep = 0; rep < 8; ++rep) {
            int e = rep * 2048 + t * 8;
            *(half8v*)&wlds[e] = *(const half8v*)(WtF + khalf * 16384 + e);
        }
        __syncthreads();

        const unsigned short* Asrc = khalf ? Xop : Agg;
#pragma unroll
        for (int ks4 = 0; ks4 < 4; ++ks4) {
            half8v af[2];
#pragma unroll
            for (int m = 0; m < 2; ++m) {
                int row = rw + m * 16 + lrow;
                if (row >= N) row = N - 1;  // clamp: only pollutes discarded rows
                af[m] = *(const half8v*)(Asrc + ((size_t)row << 7) + ks4 * 32 + lk);
            }
#pragma unroll
            for (int nf = 0; nf < 8; ++nf) {
                half8v bh = *(const half8v*)&wlds[(nf * 4 + ks4) * 512 + l * 8];
#pragma unroll
                for (int m = 0; m < 2; ++m) {
                    acc[m][nf] = __builtin_amdgcn_mfma_f32_16x16x32_f16(bh, af[m], acc[m][nf], 0, 0, 0);
                }
            }
        }
    }

    // epilogue: lane holds node row = rw + m*16 + (l&15); j = nf*16 + (l>>4)*4 + r
    const int jb = (l >> 4) << 2;
#pragma unroll
    for (int nf = 0; nf < 8; ++nf) {
        float4 bv = *(const float4*)&bias[nf * 16 + jb];
#pragma unroll
        for (int m = 0; m < 2; ++m) {
            int row = rw + m * 16 + (l & 15);
            if (row < N) {
                unsigned short h0 = f2h(fmaxf(acc[m][nf][0] + bv.x, 0.f));
                unsigned short h1 = f2h(fmaxf(acc[m][nf][1] + bv.y, 0.f));
                unsigned short h2 = f2h(fmaxf(acc[m][nf][2] + bv.z, 0.f));
                unsigned short h3 = f2h(fmaxf(acc[m][nf][3] + bv.w, 0.f));
                uint2 st;
                st.x = (unsigned)h0 | ((unsigned)h1 << 16);
                st.y = (unsigned)h2 | ((unsigned)h3 << 16);
                *(uint2*)(Hout + ((size_t)row << 7) + nf * 16 + jb) = st;
            }
        }
    }
}

// ---------------------------------------------------------------- segment-mean pool of agg3 & h2
__global__ __launch_bounds__(256) void pool_kernel(const unsigned short* __restrict__ A3,
                                                   const unsigned short* __restrict__ H2,
                                                   const int* __restrict__ gstart,
                                                   float* __restrict__ pa,
                                                   float* __restrict__ ph) {
    int g = blockIdx.x >> 2, q = blockIdx.x & 3;
    int s = gstart[g], e = gstart[g + 1];
    int len = e - s;
    int cs = s + (len * q) / 4;
    int ce = s + (len * (q + 1)) / 4;
    int t = threadIdx.x;
    int cp = t & 63;   // column pair
    int rp = t >> 6;   // 0..3 row phase
    float sa0 = 0, sa1 = 0, sh0 = 0, sh1 = 0;
    for (int r = cs + rp; r < ce; r += 4) {
        unsigned ua = *(const unsigned*)(A3 + ((size_t)r << 7) + cp * 2);
        unsigned uh = *(const unsigned*)(H2 + ((size_t)r << 7) + cp * 2);
        sa0 += h2flo(ua); sa1 += h2fhi(ua);
        sh0 += h2flo(uh); sh1 += h2fhi(uh);
    }
    __shared__ float red[4][4][64];
    red[rp][0][cp] = sa0; red[rp][1][cp] = sa1;
    red[rp][2][cp] = sh0; red[rp][3][cp] = sh1;
    __syncthreads();
    if (rp == 0) {
        float ra0 = red[0][0][cp] + red[1][0][cp] + red[2][0][cp] + red[3][0][cp];
        float ra1 = red[0][1][cp] + red[1][1][cp] + red[2][1][cp] + red[3][1][cp];
        float rh0 = red[0][2][cp] + red[1][2][cp] + red[2][2][cp] + red[3][2][cp];
        float rh1 = red[0][3][cp] + red[1][3][cp] + red[2][3][cp] + red[3][3][cp];
        unsafeAtomicAdd(&pa[g * 128 + cp * 2 + 0], ra0);
        unsafeAtomicAdd(&pa[g * 128 + cp * 2 + 1], ra1);
        unsafeAtomicAdd(&ph[g * 128 + cp * 2 + 0], rh0);
        unsafeAtomicAdd(&ph[g * 128 + cp * 2 + 1], rh1);
    }
}

// ---------------------------------------------------------------- fused layer3 + readout (fp32)
__global__ __launch_bounds__(128) void final_fused(const float* __restrict__ pa,
                                                   const float* __restrict__ ph,
                                                   const float* __restrict__ gcnt,
                                                   const float* __restrict__ W3l,
                                                   const float* __restrict__ W3r,
                                                   const float* __restrict__ b3,
                                                   const float* __restrict__ Wout,
                                                   const float* __restrict__ bout,
                                                   float* __restrict__ out) {
    __shared__ float sA[FDIM], sH[FDIM], sT[FDIM];
    int g = blockIdx.x;
    int j = threadIdx.x;
    float inv = 1.0f / fmaxf(gcnt[g], 1.0f);
    sA[j] = pa[g * FDIM + j] * inv;
    sH[j] = ph[g * FDIM + j] * inv;
    __syncthreads();
    float acc = b3[j];
    for (int c = 0; c < FDIM; ++c)
        acc += sA[c] * W3l[c * FDIM + j] + sH[c] * W3r[c * FDIM + j];
    sT[j] = acc;   // no relu on layer 3
    __syncthreads();
    if (j < 10) {
        float o = bout[j];
        for (int c = 0; c < FDIM; ++c) o += sT[c] * Wout[c * 10 + j];
        out[g * 10 + j] = o;
    }
}

extern "C" void kernel_launch(void* const* d_in, const int* in_sizes, int n_in,
                              void* d_out, int out_size, void* d_ws, size_t ws_size,
                              hipStream_t stream) {
    const float* x     = (const float*)d_in[0];
    const int*   edge  = (const int*)d_in[1];
    const int*   batch = (const int*)d_in[2];
    const float* W1l = (const float*)d_in[3];
    const float* b1  = (const float*)d_in[4];
    const float* W1r = (const float*)d_in[5];
    const float* W2l = (const float*)d_in[6];
    const float* b2  = (const float*)d_in[7];
    const float* W2r = (const float*)d_in[8];
    const float* W3l = (const float*)d_in[9];
    const float* b3  = (const float*)d_in[10];
    const float* W3r = (const float*)d_in[11];
    const float* Wout = (const float*)d_in[12];
    const float* bout = (const float*)d_in[13];
    float* out = (float*)d_out;

    const int N = N_NODES_C;
    const int E = in_sizes[1] / 2;
    const int* src = edge;
    const int* tgt = edge + E;

    // ---- workspace layout
    char* ws = (char*)d_ws;
    size_t off = 0;
    auto carve = [&](size_t bytes) { char* p = ws + off; off += (bytes + 255) & ~(size_t)255; return p; };
    int*   degi = (int*)carve((size_t)N * 4);
    int*   rs   = (int*)carve((size_t)(N + 1) * 4);
    int*   cur  = (int*)carve((size_t)N * 4);
    int*   bsum = (int*)carve(1024);
    float* invd = (float*)carve((size_t)N * 4);
    int*   gstart = (int*)carve(65 * 4);
    float* gcnt = (float*)carve(64 * 4);
    float* pa   = (float*)carve((size_t)N_GRAPHS_C * FDIM * 4);
    float* ph   = (float*)carve((size_t)N_GRAPHS_C * FDIM * 4);
    unsigned short* wt1 = (unsigned short*)carve(32768 * 2);
    unsigned short* wt2 = (unsigned short*)carve(32768 * 2);
    int*   csr  = (int*)carve((size_t)E * 4);
    unsigned short* B0 = (unsigned short*)carve((size_t)N * FDIM * 2);
    unsigned short* B1 = (unsigned short*)carve((size_t)N * FDIM * 2);
    unsigned short* B2 = (unsigned short*)carve((size_t)N * FDIM * 2);

    // ---- zero init
    hipMemsetAsync(degi, 0, (size_t)N * 4, stream);
    hipMemsetAsync(cur, 0, (size_t)N * 4, stream);
    hipMemsetAsync(pa, 0, (size_t)N_GRAPHS_C * FDIM * 4, stream);
    hipMemsetAsync(ph, 0, (size_t)N_GRAPHS_C * FDIM * 4, stream);

    // ---- CSR build + degree (XCD-partitioned atomics)
    hist_part<<<PART_BLOCKS * NXCD, 256, 0, stream>>>(tgt, degi, E);
    const int NB = (N + 1023) / 1024;
    scan_block<<<NB, 256, 0, stream>>>(degi, rs, bsum, N);
    scan_sums<<<1, 256, 0, stream>>>(bsum, NB);
    scan_add<<<(N + 255) / 256, 256, 0, stream>>>(rs, bsum, degi, invd, N, E);
    graph_cnt_kernel<<<1, 64, 0, stream>>>(batch, gstart, gcnt, N);
    scatter_part<<<PART_BLOCKS * NXCD, 256, 0, stream>>>(src, tgt, rs, cur, csr, E);

    // ---- conversions / weight prep
    conv_f16<<<(N * FDIM / 8 + 255) / 256, 256, 0, stream>>>(x, B0, N * FDIM / 8);
    prep_w<<<128, 256, 0, stream>>>(W1l, W1r, wt1);
    prep_w<<<128, 256, 0, stream>>>(W2l, W2r, wt2);

    const int aggGrid = (N + 15) / 16;
    const int gemmGrid = (N + 127) / 128;

    // ---- layer 1: agg1 -> B1 ; h1 = relu([B1|B0]@W1+b1) -> B2
    agg_f16<<<aggGrid, 256, 0, stream>>>(B0, csr, rs, invd, B1, N);
    gemm_mfma<<<gemmGrid, 256, 0, stream>>>(B1, B0, wt1, b1, B2, N);

    // ---- layer 2: agg2 -> B1 ; h2 = relu([B1|B2]@W2+b2) -> B0
    agg_f16<<<aggGrid, 256, 0, stream>>>(B2, csr, rs, invd, B1, N);
    gemm_mfma<<<gemmGrid, 256, 0, stream>>>(B1, B2, wt2, b2, B0, N);

    // ---- layer 3 folded through pooling: agg3 -> B1 ; pool agg3 & h2
    agg_f16<<<aggGrid, 256, 0, stream>>>(B0, csr, rs, invd, B1, N);
    pool_kernel<<<N_GRAPHS_C * 4, 256, 0, stream>>>(B1, B0, gstart, pa, ph);

    // ---- layer-3 GEMM (64 rows) + readout, full fp32
    final_fused<<<N_GRAPHS_C, 128, 0, stream>>>(pa, ph, gcnt, W3l, W3r, b3, Wout, bout, out);
}

// Round 7
// 245.852 us; speedup vs baseline: 1.2065x; 1.2065x over previous
//
#include <hip/hip_runtime.h>
#include <hip/hip_bf16.h>

#define N_NODES_C 100000
#define N_GRAPHS_C 64
#define FDIM 128
#define NPB 512                 // nodes per bucket
#define NBUCK 196               // ceil(100000/512)
#define SB 256                  // scatter blocks (K1/K2)

typedef _Float16 half8v __attribute__((ext_vector_type(8)));
typedef __attribute__((ext_vector_type(4))) float f32x4;

__device__ __forceinline__ unsigned short f2h(float f) {
    union { _Float16 h; unsigned short u; } v; v.h = (_Float16)f; return v.u;
}
__device__ __forceinline__ float h2flo(unsigned u) {
    union { unsigned short s; _Float16 h; } v; v.s = (unsigned short)u; return (float)v.h;
}
__device__ __forceinline__ float h2fhi(unsigned u) {
    union { unsigned short s; _Float16 h; } v; v.s = (unsigned short)(u >> 16); return (float)v.h;
}

// ================================================================ CSR build (bucketed, LDS atomics)
// K1: per-block bucket histogram
__global__ __launch_bounds__(256) void bucket_count(const int* __restrict__ tgt,
                                                    int* __restrict__ blockCnt, int E) {
    __shared__ int cnt[NBUCK];
    const int t = threadIdx.x;
    const int blk = blockIdx.x;
    if (t < NBUCK) cnt[t] = 0;
    __syncthreads();
    const int chunk = (E + SB - 1) / SB;
    const int base = blk * chunk;
    const int lim = min(E, base + chunk);
    for (int e = base + t; e < lim; e += 256) {
        atomicAdd(&cnt[tgt[e] >> 9], 1);
    }
    __syncthreads();
    if (t < NBUCK) blockCnt[t * SB + blk] = cnt[t];   // bucket-major
}

// scanA: per-bucket exclusive scan over its SB block counts (in place), total out
__global__ __launch_bounds__(256) void scanA(int* __restrict__ blockCnt,
                                             int* __restrict__ bucketTot) {
    __shared__ int s[256];
    const int t = threadIdx.x;
    const int b = blockIdx.x;
    int v = blockCnt[b * SB + t];
    s[t] = v;
    __syncthreads();
    for (int off = 1; off < 256; off <<= 1) {
        int u = (t >= off) ? s[t - off] : 0;
        __syncthreads();
        s[t] += u;
        __syncthreads();
    }
    blockCnt[b * SB + t] = s[t] - v;   // exclusive
    if (t == 255) bucketTot[b] = s[255];
}

// scanB: exclusive scan of 196 bucket totals -> bucketBase[0..196]
__global__ __launch_bounds__(256) void scanB(const int* __restrict__ bucketTot,
                                             int* __restrict__ bucketBase, int E) {
    __shared__ int s[256];
    const int t = threadIdx.x;
    int v = (t < NBUCK) ? bucketTot[t] : 0;
    s[t] = v;
    __syncthreads();
    for (int off = 1; off < 256; off <<= 1) {
        int u = (t >= off) ? s[t - off] : 0;
        __syncthreads();
        s[t] += u;
        __syncthreads();
    }
    if (t < NBUCK) bucketBase[t] = s[t] - v;
    if (t == 0) bucketBase[NBUCK] = E;
}

// K2: scatter (tgt,src) pairs into bucket-contiguous staging; rank via LDS atomics
__global__ __launch_bounds__(256) void bucket_scatter(const int* __restrict__ src,
                                                      const int* __restrict__ tgt,
                                                      const int* __restrict__ blockCnt,
                                                      const int* __restrict__ bucketBase,
                                                      uint2* __restrict__ staged, int E) {
    __shared__ int lcur[NBUCK];
    const int t = threadIdx.x;
    const int blk = blockIdx.x;
    if (t < NBUCK) lcur[t] = bucketBase[t] + blockCnt[t * SB + blk];
    __syncthreads();
    const int chunk = (E + SB - 1) / SB;
    const int base = blk * chunk;
    const int lim = min(E, base + chunk);
    for (int e = base + t; e < lim; e += 256) {
        int tv = tgt[e];
        int pos = atomicAdd(&lcur[tv >> 9], 1);
        uint2 p; p.x = (unsigned)tv; p.y = (unsigned)src[e];
        staged[pos] = p;
    }
}

// K3: per bucket: per-node degree (LDS), LDS scan -> rowstart+invd, LDS-cursor scatter -> csr
__global__ __launch_bounds__(256) void bucket_finalize(const uint2* __restrict__ staged,
                                                       const int* __restrict__ bucketBase,
                                                       int* __restrict__ rs,
                                                       float* __restrict__ invd,
                                                       int* __restrict__ csr, int N, int E) {
    __shared__ int dcnt[NPB];
    __shared__ int pref[NPB];
    __shared__ int ts[256];
    const int t = threadIdx.x;
    const int b = blockIdx.x;
    const int s = bucketBase[b];
    const int e = bucketBase[b + 1];
    const int nb0 = b * NPB;
    const int nn = min(NPB, N - nb0);   // nodes in this bucket

    dcnt[t] = 0; dcnt[t + 256] = 0;
    __syncthreads();
    for (int i = s + t; i < e; i += 256)
        atomicAdd(&dcnt[(int)staged[i].x - nb0], 1);
    __syncthreads();

    // exclusive scan of 512 via 256 threads
    int a0 = dcnt[2 * t], a1 = dcnt[2 * t + 1];
    ts[t] = a0 + a1;
    __syncthreads();
    for (int off = 1; off < 256; off <<= 1) {
        int u = (t >= off) ? ts[t - off] : 0;
        __syncthreads();
        ts[t] += u;
        __syncthreads();
    }
    int excl = (t > 0) ? ts[t - 1] : 0;
    pref[2 * t] = excl;
    pref[2 * t + 1] = excl + a0;
    __syncthreads();

    // write rowstart + inv_deg
    if (t < nn) {
        rs[nb0 + t] = s + pref[t];
        invd[nb0 + t] = 1.0f / (float)max(dcnt[t], 1);
    }
    int t2 = t + 256;
    if (t2 < nn) {
        rs[nb0 + t2] = s + pref[t2];
        invd[nb0 + t2] = 1.0f / (float)max(dcnt[t2], 1);
    }
    if (b == 0 && t == 0) rs[N] = E;
    __syncthreads();

    // reuse dcnt as running cursor = pref
    dcnt[t] = pref[t]; dcnt[t + 256] = pref[t + 256];
    __syncthreads();
    for (int i = s + t; i < e; i += 256) {
        uint2 p = staged[i];
        int r = atomicAdd(&dcnt[(int)p.x - nb0], 1);
        csr[s + r] = (int)p.y;
    }
}

// ---------------------------------------------------------------- graph boundaries (batch sorted)
__global__ __launch_bounds__(64) void graph_cnt_kernel(const int* __restrict__ batch,
                                                       int* __restrict__ gstart,
                                                       float* __restrict__ gcnt, int n) {
    int g = threadIdx.x;  // 0..63
    int lo = 0, hi = n;
    while (lo < hi) { int m = (lo + hi) >> 1; if (batch[m] < g) lo = m + 1; else hi = m; }
    int lb = lo;
    lo = 0; hi = n;
    while (lo < hi) { int m = (lo + hi) >> 1; if (batch[m] < g + 1) lo = m + 1; else hi = m; }
    gstart[g] = lb;
    gcnt[g] = (float)(lo - lb);
    if (g == 0) gstart[64] = n;
}

// ---------------------------------------------------------------- fp32 -> fp16 convert (8/thread)
__global__ __launch_bounds__(256) void conv_f16(const float* __restrict__ in,
                                                unsigned short* __restrict__ out, int n8) {
    int i = blockIdx.x * 256 + threadIdx.x;
    if (i < n8) {
        float4 v0 = *(const float4*)(in + (size_t)i * 8);
        float4 v1 = *(const float4*)(in + (size_t)i * 8 + 4);
        half8v o;
        o[0] = (_Float16)v0.x; o[1] = (_Float16)v0.y; o[2] = (_Float16)v0.z; o[3] = (_Float16)v0.w;
        o[4] = (_Float16)v1.x; o[5] = (_Float16)v1.y; o[6] = (_Float16)v1.z; o[7] = (_Float16)v1.w;
        *(half8v*)(out + (size_t)i * 8) = o;
    }
}

// ---------------------------------------------------------------- weight prep: fragment-ordered fp16
__global__ __launch_bounds__(256) void prep_w(const float* __restrict__ Wl,
                                              const float* __restrict__ Wr,
                                              unsigned short* __restrict__ outW) {
    int id = blockIdx.x * 256 + threadIdx.x;  // 0..32767
    int c = id >> 9, i = id & 511;
    int l = i >> 3, e = i & 7;
    int khalf = c >> 5, nf = (c >> 2) & 7, ks4 = c & 3;
    int j = nf * 16 + (l & 15);
    int k = khalf * 128 + ks4 * 32 + ((l >> 4) << 3) + e;
    float w = (k < 128) ? Wl[k * 128 + j] : Wr[(k - 128) * 128 + j];
    outW[id] = f2h(w);
}

// ---------------------------------------------------------------- CSR mean-aggregate (fp16 in/out)
__device__ __forceinline__ void acc8h(float* a, half8v v) {
#pragma unroll
    for (int j = 0; j < 8; ++j) a[j] += (float)v[j];
}

__global__ __launch_bounds__(256) void agg_f16(const unsigned short* __restrict__ Xin,
                                               const int* __restrict__ csr,
                                               const int* __restrict__ rowstart,
                                               const float* __restrict__ invd,
                                               unsigned short* __restrict__ Agg, int N) {
    const int grp  = threadIdx.x >> 4;            // 0..15
    const int node = blockIdx.x * 16 + grp;
    if (node >= N) return;
    const int lane = threadIdx.x & 15;
    const int beg = rowstart[node];
    const int end = rowstart[node + 1];

    float a[8] = {0.f, 0.f, 0.f, 0.f, 0.f, 0.f, 0.f, 0.f};
    int e = beg;
    for (; e + 3 < end; e += 4) {
        int s0 = csr[e + 0];
        int s1 = csr[e + 1];
        int s2 = csr[e + 2];
        int s3 = csr[e + 3];
        half8v v0 = *(const half8v*)(Xin + ((size_t)s0 << 7) + lane * 8);
        half8v v1 = *(const half8v*)(Xin + ((size_t)s1 << 7) + lane * 8);
        half8v v2 = *(const half8v*)(Xin + ((size_t)s2 << 7) + lane * 8);
        half8v v3 = *(const half8v*)(Xin + ((size_t)s3 << 7) + lane * 8);
        acc8h(a, v0); acc8h(a, v1); acc8h(a, v2); acc8h(a, v3);
    }
    for (; e < end; ++e) {
        int s0 = csr[e];
        half8v v0 = *(const half8v*)(Xin + ((size_t)s0 << 7) + lane * 8);
        acc8h(a, v0);
    }

    float sc = invd[node];
    half8v o;
#pragma unroll
    for (int j = 0; j < 8; ++j) o[j] = (_Float16)(a[j] * sc);
    *(half8v*)(Agg + ((size_t)node << 7) + lane * 8) = o;
}

// ---------------------------------------------------------------- MFMA dual GEMM (fp16)
// H[r,:] = relu( [Agg(r)|X(r)] @ W + b ), virtual K=256. 4 waves; wave owns 32 rows.
// Swapped operands => D^T: lane holds one node-row, 4 consecutive j-cols -> 8B stores.
__global__ __launch_bounds__(256) void gemm_mfma(const unsigned short* __restrict__ Agg,
                                                 const unsigned short* __restrict__ Xop,
                                                 const unsigned short* __restrict__ WtF,
                                                 const float* __restrict__ bias,
                                                 unsigned short* __restrict__ Hout, int N) {
    __shared__ unsigned short wlds[32 * 512];   // 32 KiB: one khalf, fragment-ordered

    const int t = threadIdx.x;
    const int wave = t >> 6;
    const int l = t & 63;
    const int rw = blockIdx.x * 128 + wave * 32;
    const int lrow = l & 15;
    const int lk = (l >> 4) << 3;

    f32x4 acc[2][8];
#pragma unroll
    for (int m = 0; m < 2; ++m)
#pragma unroll
        for (int nf = 0; nf < 8; ++nf) acc[m][nf] = (f32x4)(0.f);

    for (int khalf = 0; khalf < 2; ++khalf) {
        if (khalf) __syncthreads();
#pragma unroll
        for (int rep = 0; rep < 8; ++rep) {
            int e = rep * 2048 + t * 8;
            *(half8v*)&wlds[e] = *(const half8v*)(WtF + khalf * 16384 + e);
        }
        __syncthreads();

        const unsigned short* Asrc = khalf ? Xop : Agg;
#pragma unroll
        for (int ks4 = 0; ks4 < 4; ++ks4) {
            half8v af[2];
#pragma unroll
            for (int m = 0; m < 2; ++m) {
                int row = rw + m * 16 + lrow;
                if (row >= N) row = N - 1;
                af[m] = *(const half8v*)(Asrc + ((size_t)row << 7) + ks4 * 32 + lk);
            }
#pragma unroll
            for (int nf = 0; nf < 8; ++nf) {
                half8v bh = *(const half8v*)&wlds[(nf * 4 + ks4) * 512 + l * 8];
#pragma unroll
                for (int m = 0; m < 2; ++m) {
                    acc[m][nf] = __builtin_amdgcn_mfma_f32_16x16x32_f16(bh, af[m], acc[m][nf], 0, 0, 0);
                }
            }
        }
    }

    const int jb = (l >> 4) << 2;
#pragma unroll
    for (int nf = 0; nf < 8; ++nf) {
        float4 bv = *(const float4*)&bias[nf * 16 + jb];
#pragma unroll
        for (int m = 0; m < 2; ++m) {
            int row = rw + m * 16 + (l & 15);
            if (row < N) {
                unsigned short h0 = f2h(fmaxf(acc[m][nf][0] + bv.x, 0.f));
                unsigned short h1 = f2h(fmaxf(acc[m][nf][1] + bv.y, 0.f));
                unsigned short h2 = f2h(fmaxf(acc[m][nf][2] + bv.z, 0.f));
                unsigned short h3 = f2h(fmaxf(acc[m][nf][3] + bv.w, 0.f));
                uint2 st;
                st.x = (unsigned)h0 | ((unsigned)h1 << 16);
                st.y = (unsigned)h2 | ((unsigned)h3 << 16);
                *(uint2*)(Hout + ((size_t)row << 7) + nf * 16 + jb) = st;
            }
        }
    }
}

// ---------------------------------------------------------------- segment-mean pool of agg3 & h2
__global__ __launch_bounds__(256) void pool_kernel(const unsigned short* __restrict__ A3,
                                                   const unsigned short* __restrict__ H2,
                                                   const int* __restrict__ gstart,
                                                   float* __restrict__ pa,
                                                   float* __restrict__ ph) {
    int g = blockIdx.x >> 2, q = blockIdx.x & 3;
    int s = gstart[g], e = gstart[g + 1];
    int len = e - s;
    int cs = s + (len * q) / 4;
    int ce = s + (len * (q + 1)) / 4;
    int t = threadIdx.x;
    int cp = t & 63;
    int rp = t >> 6;
    float sa0 = 0, sa1 = 0, sh0 = 0, sh1 = 0;
    for (int r = cs + rp; r < ce; r += 4) {
        unsigned ua = *(const unsigned*)(A3 + ((size_t)r << 7) + cp * 2);
        unsigned uh = *(const unsigned*)(H2 + ((size_t)r << 7) + cp * 2);
        sa0 += h2flo(ua); sa1 += h2fhi(ua);
        sh0 += h2flo(uh); sh1 += h2fhi(uh);
    }
    __shared__ float red[4][4][64];
    red[rp][0][cp] = sa0; red[rp][1][cp] = sa1;
    red[rp][2][cp] = sh0; red[rp][3][cp] = sh1;
    __syncthreads();
    if (rp == 0) {
        float ra0 = red[0][0][cp] + red[1][0][cp] + red[2][0][cp] + red[3][0][cp];
        float ra1 = red[0][1][cp] + red[1][1][cp] + red[2][1][cp] + red[3][1][cp];
        float rh0 = red[0][2][cp] + red[1][2][cp] + red[2][2][cp] + red[3][2][cp];
        float rh1 = red[0][3][cp] + red[1][3][cp] + red[2][3][cp] + red[3][3][cp];
        unsafeAtomicAdd(&pa[g * 128 + cp * 2 + 0], ra0);
        unsafeAtomicAdd(&pa[g * 128 + cp * 2 + 1], ra1);
        unsafeAtomicAdd(&ph[g * 128 + cp * 2 + 0], rh0);
        unsafeAtomicAdd(&ph[g * 128 + cp * 2 + 1], rh1);
    }
}

// ---------------------------------------------------------------- fused layer3 + readout (fp32)
__global__ __launch_bounds__(128) void final_fused(const float* __restrict__ pa,
                                                   const float* __restrict__ ph,
                                                   const float* __restrict__ gcnt,
                                                   const float* __restrict__ W3l,
                                                   const float* __restrict__ W3r,
                                                   const float* __restrict__ b3,
                                                   const float* __restrict__ Wout,
                                                   const float* __restrict__ bout,
                                                   float* __restrict__ out) {
    __shared__ float sA[FDIM], sH[FDIM], sT[FDIM];
    int g = blockIdx.x;
    int j = threadIdx.x;
    float inv = 1.0f / fmaxf(gcnt[g], 1.0f);
    sA[j] = pa[g * FDIM + j] * inv;
    sH[j] = ph[g * FDIM + j] * inv;
    __syncthreads();
    float acc = b3[j];
    for (int c = 0; c < FDIM; ++c)
        acc += sA[c] * W3l[c * FDIM + j] + sH[c] * W3r[c * FDIM + j];
    sT[j] = acc;
    __syncthreads();
    if (j < 10) {
        float o = bout[j];
        for (int c = 0; c < FDIM; ++c) o += sT[c] * Wout[c * 10 + j];
        out[g * 10 + j] = o;
    }
}

extern "C" void kernel_launch(void* const* d_in, const int* in_sizes, int n_in,
                              void* d_out, int out_size, void* d_ws, size_t ws_size,
                              hipStream_t stream) {
    const float* x     = (const float*)d_in[0];
    const int*   edge  = (const int*)d_in[1];
    const int*   batch = (const int*)d_in[2];
    const float* W1l = (const float*)d_in[3];
    const float* b1  = (const float*)d_in[4];
    const float* W1r = (const float*)d_in[5];
    const float* W2l = (const float*)d_in[6];
    const float* b2  = (const float*)d_in[7];
    const float* W2r = (const float*)d_in[8];
    const float* W3l = (const float*)d_in[9];
    const float* b3  = (const float*)d_in[10];
    const float* W3r = (const float*)d_in[11];
    const float* Wout = (const float*)d_in[12];
    const float* bout = (const float*)d_in[13];
    float* out = (float*)d_out;

    const int N = N_NODES_C;
    const int E = in_sizes[1] / 2;
    const int* src = edge;
    const int* tgt = edge + E;

    // ---- workspace layout
    char* ws = (char*)d_ws;
    size_t off = 0;
    auto carve = [&](size_t bytes) { char* p = ws + off; off += (bytes + 255) & ~(size_t)255; return p; };
    int*   rs   = (int*)carve((size_t)(N + 1) * 4);
    float* invd = (float*)carve((size_t)N * 4);
    int*   gstart = (int*)carve(65 * 4);
    float* gcnt = (float*)carve(64 * 4);
    float* pa   = (float*)carve((size_t)N_GRAPHS_C * FDIM * 4);
    float* ph   = (float*)carve((size_t)N_GRAPHS_C * FDIM * 4);
    unsigned short* wt1 = (unsigned short*)carve(32768 * 2);
    unsigned short* wt2 = (unsigned short*)carve(32768 * 2);
    int*   blockCnt  = (int*)carve((size_t)NBUCK * SB * 4);
    int*   bucketTot = (int*)carve(NBUCK * 4);
    int*   bucketBase = (int*)carve((NBUCK + 1) * 4);
    uint2* staged = (uint2*)carve((size_t)E * 8);
    int*   csr  = (int*)carve((size_t)E * 4);
    unsigned short* B0 = (unsigned short*)carve((size_t)N * FDIM * 2);
    unsigned short* B1 = (unsigned short*)carve((size_t)N * FDIM * 2);
    unsigned short* B2 = (unsigned short*)carve((size_t)N * FDIM * 2);

    // ---- zero init (pool accumulators only)
    hipMemsetAsync(pa, 0, (size_t)N_GRAPHS_C * FDIM * 4, stream);
    hipMemsetAsync(ph, 0, (size_t)N_GRAPHS_C * FDIM * 4, stream);

    // ---- conversions / weight prep (independent of CSR chain)
    conv_f16<<<(N * FDIM / 8 + 255) / 256, 256, 0, stream>>>(x, B0, N * FDIM / 8);
    prep_w<<<128, 256, 0, stream>>>(W1l, W1r, wt1);
    prep_w<<<128, 256, 0, stream>>>(W2l, W2r, wt2);
    graph_cnt_kernel<<<1, 64, 0, stream>>>(batch, gstart, gcnt, N);

    // ---- CSR build: bucket count -> scans -> staged scatter -> finalize (rs, invd, csr)
    bucket_count<<<SB, 256, 0, stream>>>(tgt, blockCnt, E);
    scanA<<<NBUCK, 256, 0, stream>>>(blockCnt, bucketTot);
    scanB<<<1, 256, 0, stream>>>(bucketTot, bucketBase, E);
    bucket_scatter<<<SB, 256, 0, stream>>>(src, tgt, blockCnt, bucketBase, staged, E);
    bucket_finalize<<<NBUCK, 256, 0, stream>>>(staged, bucketBase, rs, invd, csr, N, E);

    const int aggGrid = (N + 15) / 16;
    const int gemmGrid = (N + 127) / 128;

    // ---- layer 1: agg1 -> B1 ; h1 = relu([B1|B0]@W1+b1) -> B2
    agg_f16<<<aggGrid, 256, 0, stream>>>(B0, csr, rs, invd, B1, N);
    gemm_mfma<<<gemmGrid, 256, 0, stream>>>(B1, B0, wt1, b1, B2, N);

    // ---- layer 2: agg2 -> B1 ; h2 = relu([B1|B2]@W2+b2) -> B0
    agg_f16<<<aggGrid, 256, 0, stream>>>(B2, csr, rs, invd, B1, N);
    gemm_mfma<<<gemmGrid, 256, 0, stream>>>(B1, B2, wt2, b2, B0, N);

    // ---- layer 3 folded through pooling: agg3 -> B1 ; pool agg3 & h2
    agg_f16<<<aggGrid, 256, 0, stream>>>(B0, csr, rs, invd, B1, N);
    pool_kernel<<<N_GRAPHS_C * 4, 256, 0, stream>>>(B1, B0, gstart, pa, ph);

    // ---- layer-3 GEMM (64 rows) + readout, full fp32
    final_fused<<<N_GRAPHS_C, 128, 0, stream>>>(pa, ph, gcnt, W3l, W3r, b3, Wout, bout, out);
}